// Round 1
// baseline (4581.533 us; speedup 1.0000x reference)
//
#include <hip/hip_runtime.h>
#include <hip/hip_bf16.h>
#include <math.h>

// GPT blocks: B=4, T=2048, C=1024, FF=4096, NB=8. Single-head causal attn.
// Strategy: bf16 MFMA GEMMs (m97 structure), fp32 residual stream in d_out.

typedef __bf16 bf16;
typedef __bf16 bf16x8 __attribute__((ext_vector_type(8)));
typedef __bf16 bf16x4 __attribute__((ext_vector_type(4)));
typedef float f32x4 __attribute__((ext_vector_type(4)));

#define BM 128
#define BN 128
#define BK 32

__device__ __forceinline__ void async_load16(const void* g, void* l) {
  __builtin_amdgcn_global_load_lds(
      (const __attribute__((address_space(1))) void*)g,
      (__attribute__((address_space(3))) void*)l, 16, 0, 0);
}

constexpr int EPI_BF16 = 0;     // C = bf16(acc + bias)           (bias may be null)
constexpr int EPI_GELU = 1;     // C = bf16(gelu(acc + bias))
constexpr int EPI_RESID = 2;    // C = f32(resid + acc + bias)
constexpr int EPI_F32SCALE = 3; // C = f32(acc * alpha)

// C[M,N] = A[M,K] @ B[N,K]^T ; all tiles full (M,N mult of 128, K mult of 32)
template <int EPI>
__global__ __launch_bounds__(256) void gemm_bt(
    const bf16* __restrict__ A, const bf16* __restrict__ Bw,
    const float* __restrict__ bias, const float* __restrict__ resid,
    void* __restrict__ Cout, int K, int lda, int ldb, int ldc,
    long batchA, long batchB, long batchC, float alpha,
    int causalSkip, int kLimit) {
  const int m0 = blockIdx.y * BM;
  const int n0 = blockIdx.x * BN;
  if (causalSkip && n0 > m0) return;  // fully-masked score tile
  const int bz = blockIdx.z;
  const bf16* Ab = A + (long)bz * batchA;
  const bf16* Bb = Bw + (long)bz * batchB;
  const int kEnd = kLimit ? ((m0 + BM < K) ? (m0 + BM) : K) : K;

  __shared__ bf16 As[BM * BK];
  __shared__ bf16 Bs[BN * BK];

  const int tid = threadIdx.x;
  const int wave = tid >> 6;
  const int lane = tid & 63;
  const int wr = wave >> 1;   // wave row in 2x2
  const int wc = wave & 1;    // wave col
  const int l16 = lane & 15;
  const int kq = (lane >> 4) * 8;

  f32x4 acc[4][4] = {};

  for (int k0 = 0; k0 < kEnd; k0 += BK) {
    // stage A,B tiles: 512 chunks of 16B each, 256 threads x 2 reps
#pragma unroll
    for (int rep = 0; rep < 2; rep++) {
      const int c = tid + rep * 256;
      const int r = c >> 2;
      const int ck = (c & 3) << 3;
      const bf16* gA = Ab + (long)(m0 + r) * lda + (k0 + ck);
      const bf16* gB = Bb + (long)(n0 + r) * ldb + (k0 + ck);
      bf16* lA = As + (c & ~63) * 8;  // wave-uniform base; HW adds lane*16B
      bf16* lB = Bs + (c & ~63) * 8;
      async_load16(gA, lA);
      async_load16(gB, lB);
    }
    __syncthreads();  // drains vmcnt(0): LDS data visible
    bf16x8 af[4], bfr[4];
#pragma unroll
    for (int i = 0; i < 4; i++)
      af[i] = *(const bf16x8*)(As + (wr * 64 + i * 16 + l16) * BK + kq);
#pragma unroll
    for (int j = 0; j < 4; j++)
      bfr[j] = *(const bf16x8*)(Bs + (wc * 64 + j * 16 + l16) * BK + kq);
#pragma unroll
    for (int i = 0; i < 4; i++)
#pragma unroll
      for (int j = 0; j < 4; j++)
        acc[i][j] = __builtin_amdgcn_mfma_f32_16x16x32_bf16(af[i], bfr[j],
                                                            acc[i][j], 0, 0, 0);
    __syncthreads();  // all reads done before next stage overwrites LDS
  }

  // C/D layout: col = lane&15, row = (lane>>4)*4 + reg  [m89/m91 verified]
  const int baseRow = m0 + wr * 64 + (lane >> 4) * 4;
  const int baseCol = n0 + wc * 64 + l16;
#pragma unroll
  for (int j = 0; j < 4; j++) {
    const int col = baseCol + j * 16;
    float bv = 0.0f;
    if (EPI != EPI_F32SCALE && bias != nullptr) bv = bias[col];
#pragma unroll
    for (int i = 0; i < 4; i++) {
      const int row0 = baseRow + i * 16;
#pragma unroll
      for (int r = 0; r < 4; r++) {
        const float v = acc[i][j][r];
        const long idx = (long)bz * batchC + (long)(row0 + r) * ldc + col;
        if (EPI == EPI_F32SCALE) {
          ((float*)Cout)[idx] = v * alpha;
        } else if (EPI == EPI_RESID) {
          ((float*)Cout)[idx] = resid[idx] + v + bv;
        } else if (EPI == EPI_GELU) {
          const float u = v + bv;
          const float g = 0.5f * u * (1.0f + erff(u * 0.70710678118654752f));
          ((bf16*)Cout)[idx] = (bf16)g;
        } else {
          ((bf16*)Cout)[idx] = (bf16)(v + bv);
        }
      }
    }
  }
}

// LayerNorm: one block per row of 1024, fp32 in -> bf16 out
__global__ __launch_bounds__(256) void ln_kernel(
    const float* __restrict__ x, const float* __restrict__ w,
    const float* __restrict__ b, bf16* __restrict__ out) {
  const int C = 1024;
  const long row = blockIdx.x;
  const int t = threadIdx.x;
  const float4 v = ((const float4*)(x + row * C))[t];
  float s = v.x + v.y + v.z + v.w;
  float sq = v.x * v.x + v.y * v.y + v.z * v.z + v.w * v.w;
#pragma unroll
  for (int o = 1; o < 64; o <<= 1) {
    s += __shfl_xor(s, o, 64);
    sq += __shfl_xor(sq, o, 64);
  }
  __shared__ float rs[4], rq[4];
  const int wv = t >> 6, ln = t & 63;
  if (!ln) { rs[wv] = s; rq[wv] = sq; }
  __syncthreads();
  s = rs[0] + rs[1] + rs[2] + rs[3];
  sq = rq[0] + rq[1] + rq[2] + rq[3];
  const float mean = s * (1.0f / 1024.0f);
  const float var = sq * (1.0f / 1024.0f) - mean * mean;
  const float rstd = rsqrtf(var + 1e-5f);
  const float4 wv4 = ((const float4*)w)[t];
  const float4 bv4 = ((const float4*)b)[t];
  bf16x4 o = {(bf16)((v.x - mean) * rstd * wv4.x + bv4.x),
              (bf16)((v.y - mean) * rstd * wv4.y + bv4.y),
              (bf16)((v.z - mean) * rstd * wv4.z + bv4.z),
              (bf16)((v.w - mean) * rstd * wv4.w + bv4.w)};
  ((bf16x4*)(out + row * C))[t] = o;
}

// Causal softmax over fp32 scores row (already scaled) -> bf16 P, zeros for s>t
__global__ __launch_bounds__(256) void softmax_causal(
    const float* __restrict__ S, bf16* __restrict__ P) {
  const int T = 2048;
  const int t = blockIdx.x, b = blockIdx.y;
  const long rowoff = ((long)b * T + t) * (long)T;
  const float* row = S + rowoff;
  bf16* prow = P + rowoff;
  const int L = t + 1;
  const int tid = threadIdx.x;
  float vals[8];
  float mx = -1e30f;
#pragma unroll
  for (int i = 0; i < 8; i++) {
    const int idx = tid + i * 256;
    if (idx < L) {
      vals[i] = row[idx];
      mx = fmaxf(mx, vals[i]);
    } else {
      vals[i] = -1e30f;
    }
  }
#pragma unroll
  for (int o = 1; o < 64; o <<= 1) mx = fmaxf(mx, __shfl_xor(mx, o, 64));
  __shared__ float red[4], red2[4];
  const int wv = tid >> 6, ln = tid & 63;
  if (!ln) red[wv] = mx;
  __syncthreads();
  mx = fmaxf(fmaxf(red[0], red[1]), fmaxf(red[2], red[3]));
  float sum = 0.0f;
#pragma unroll
  for (int i = 0; i < 8; i++) {
    const int idx = tid + i * 256;
    const float e = (idx < L) ? __expf(vals[i] - mx) : 0.0f;
    vals[i] = e;
    sum += e;
  }
#pragma unroll
  for (int o = 1; o < 64; o <<= 1) sum += __shfl_xor(sum, o, 64);
  if (!ln) red2[wv] = sum;
  __syncthreads();
  sum = red2[0] + red2[1] + red2[2] + red2[3];
  const float inv = 1.0f / sum;
#pragma unroll
  for (int i = 0; i < 8; i++) prow[tid + i * 256] = (bf16)(vals[i] * inv);
}

// V transpose: qkv[b, s, 2048+c] -> vt[b, c, s]  (bf16)
__global__ __launch_bounds__(256) void transpose_v(
    const bf16* __restrict__ qkv, bf16* __restrict__ vt) {
  const int T = 2048, C3 = 3072, C = 1024, COFF = 2048;
  __shared__ bf16 tile[32][33];
  const int b = blockIdx.z;
  const int s0 = blockIdx.x * 32, c0 = blockIdx.y * 32;
  const int tx = threadIdx.x & 31, ty0 = threadIdx.x >> 5;
#pragma unroll
  for (int j = 0; j < 4; j++) {
    const int ty = ty0 + j * 8;
    tile[ty][tx] = qkv[((long)b * T + s0 + ty) * C3 + COFF + c0 + tx];
  }
  __syncthreads();
#pragma unroll
  for (int j = 0; j < 4; j++) {
    const int ty = ty0 + j * 8;
    vt[(long)b * C * T + (long)(c0 + ty) * T + s0 + tx] = tile[tx][ty];
  }
}

__global__ void f2bf_kernel(const float* __restrict__ in,
                            bf16* __restrict__ out, long n4) {
  const long i = (long)blockIdx.x * blockDim.x + threadIdx.x;
  if (i < n4) {
    const float4 v = ((const float4*)in)[i];
    bf16x4 o = {(bf16)v.x, (bf16)v.y, (bf16)v.z, (bf16)v.w};
    ((bf16x4*)out)[i] = o;
  }
}

extern "C" void kernel_launch(void* const* d_in, const int* in_sizes, int n_in,
                              void* d_out, int out_size, void* d_ws,
                              size_t ws_size, hipStream_t stream) {
  const int Bb = 4, T = 2048, C = 1024, FF = 4096, NB = 8;
  const int M = Bb * T;  // 8192
  const float* x_in = (const float*)d_in[0];
  const float* ln1_w = (const float*)d_in[1];
  const float* ln1_b = (const float*)d_in[2];
  const float* qkv_w = (const float*)d_in[3];
  const float* qkv_b = (const float*)d_in[4];
  const float* out_w = (const float*)d_in[5];
  const float* out_b = (const float*)d_in[6];
  const float* ln2_w = (const float*)d_in[7];
  const float* ln2_b = (const float*)d_in[8];
  const float* ff0_w = (const float*)d_in[9];
  const float* ff0_b = (const float*)d_in[10];
  const float* ff3_w = (const float*)d_in[11];
  const float* ff3_b = (const float*)d_in[12];
  float* x = (float*)d_out;  // fp32 residual stream lives in d_out

  char* p = (char*)d_ws;
  auto alloc = [&](size_t bytes) {
    char* r = p;
    p += (bytes + 255) & ~(size_t)255;
    return r;
  };
  bf16* wqkv = (bf16*)alloc((size_t)NB * 3 * C * C * 2);
  bf16* wout = (bf16*)alloc((size_t)NB * C * C * 2);
  bf16* wff0 = (bf16*)alloc((size_t)NB * FF * C * 2);
  bf16* wff3 = (bf16*)alloc((size_t)NB * C * FF * 2);
  bf16* hbuf = (bf16*)alloc((size_t)M * C * 2);
  bf16* qkvb = (bf16*)alloc((size_t)M * 3 * C * 2);
  float* att = (float*)alloc((size_t)Bb * T * T * 4);
  bf16* pbuf = (bf16*)alloc((size_t)Bb * T * T * 2);
  bf16* vt = (bf16*)alloc((size_t)Bb * C * T * 2);
  bf16* aout = (bf16*)alloc((size_t)M * C * 2);
  bf16* ffb = (bf16*)att;  // FF intermediate aliases scores buffer (phase-disjoint)

  auto conv = [&](const float* src, bf16* dst, long n) {
    const long n4 = n / 4;
    f2bf_kernel<<<dim3((unsigned)((n4 + 255) / 256)), dim3(256), 0, stream>>>(
        src, dst, n4);
  };
  conv(qkv_w, wqkv, (long)NB * 3 * C * C);
  conv(out_w, wout, (long)NB * C * C);
  conv(ff0_w, wff0, (long)NB * FF * C);
  conv(ff3_w, wff3, (long)NB * C * FF);

  hipMemcpyAsync(x, x_in, (size_t)M * C * 4, hipMemcpyDeviceToDevice, stream);

  const float scale = 1.0f / 32.0f;  // 1/sqrt(C)

  for (int blk = 0; blk < NB; blk++) {
    const bf16* wq = wqkv + (long)blk * 3 * C * C;
    const bf16* wo = wout + (long)blk * C * C;
    const bf16* w0 = wff0 + (long)blk * FF * C;
    const bf16* w3 = wff3 + (long)blk * C * FF;
    const float* l1w = ln1_w + blk * C;
    const float* l1b = ln1_b + blk * C;
    const float* l2w = ln2_w + blk * C;
    const float* l2b = ln2_b + blk * C;
    const float* qb = qkv_b + blk * 3 * C;
    const float* ob = out_b + blk * C;
    const float* f0b = ff0_b + blk * FF;
    const float* f3b = ff3_b + blk * C;

    // h = LN1(x)
    ln_kernel<<<dim3(M), dim3(256), 0, stream>>>(x, l1w, l1b, hbuf);
    // qkv = h @ Wqkv^T + b
    gemm_bt<EPI_BF16><<<dim3(3 * C / BN, M / BM), dim3(256), 0, stream>>>(
        hbuf, wq, qb, nullptr, qkvb, C, C, C, 3 * C, 0, 0, 0, 1.0f, 0, 0);
    // S = q @ k^T * scale (causal tile skip), per batch
    gemm_bt<EPI_F32SCALE><<<dim3(T / BN, T / BM, Bb), dim3(256), 0, stream>>>(
        qkvb, qkvb + C, nullptr, nullptr, att, C, 3 * C, 3 * C, T,
        (long)T * 3 * C, (long)T * 3 * C, (long)T * T, scale, 1, 0);
    // P = softmax(S) causal, bf16
    softmax_causal<<<dim3(T, Bb), dim3(256), 0, stream>>>(att, pbuf);
    // vt = v^T
    transpose_v<<<dim3(T / 32, C / 32, Bb), dim3(256), 0, stream>>>(qkvb, vt);
    // attn_out = P @ V   (K limited to m0+BM by causality)
    gemm_bt<EPI_BF16><<<dim3(C / BN, T / BM, Bb), dim3(256), 0, stream>>>(
        pbuf, vt, nullptr, nullptr, aout, T, T, T, C, (long)T * T, (long)C * T,
        (long)T * C, 1.0f, 0, 1);
    // x = x + attn_out @ Wo^T + bo
    gemm_bt<EPI_RESID><<<dim3(C / BN, M / BM), dim3(256), 0, stream>>>(
        aout, wo, ob, x, x, C, C, C, C, 0, 0, 0, 1.0f, 0, 0);
    // h = LN2(x)
    ln_kernel<<<dim3(M), dim3(256), 0, stream>>>(x, l2w, l2b, hbuf);
    // ff = gelu(h @ W0^T + b0)
    gemm_bt<EPI_GELU><<<dim3(FF / BN, M / BM), dim3(256), 0, stream>>>(
        hbuf, w0, f0b, nullptr, ffb, C, C, C, FF, 0, 0, 0, 1.0f, 0, 0);
    // x = x + ff @ W3^T + b3
    gemm_bt<EPI_RESID><<<dim3(C / BN, M / BM), dim3(256), 0, stream>>>(
        ffb, w3, f3b, x, x, FF, FF, FF, C, 0, 0, 0, 1.0f, 0, 0);
  }
}

// Round 2
// 4077.253 us; speedup vs baseline: 1.1237x; 1.1237x over previous
//
#include <hip/hip_runtime.h>
#include <hip/hip_bf16.h>
#include <math.h>

// GPT blocks: B=4, T=2048, C=1024, FF=4096, NB=8. Single-head causal attn.
// bf16 MFMA GEMMs (m97 structure) + LDS XOR-swizzle (kills 8-way bank
// conflicts) + XCD-aware block remap (same-A-strip blocks share one L2).

typedef __bf16 bf16;
typedef __bf16 bf16x8 __attribute__((ext_vector_type(8)));
typedef __bf16 bf16x4 __attribute__((ext_vector_type(4)));
typedef float f32x4 __attribute__((ext_vector_type(4)));

#define BM 128
#define BN 128
#define BK 32

__device__ __forceinline__ void async_load16(const void* g, void* l) {
  __builtin_amdgcn_global_load_lds(
      (const __attribute__((address_space(1))) void*)g,
      (__attribute__((address_space(3))) void*)l, 16, 0, 0);
}

constexpr int EPI_BF16 = 0;     // C = bf16(acc + bias)           (bias may be null)
constexpr int EPI_GELU = 1;     // C = bf16(gelu(acc + bias))
constexpr int EPI_RESID = 2;    // C = f32(resid + acc + bias)
constexpr int EPI_F32SCALE = 3; // C = f32(acc * alpha)

// C[M,N] = A[M,K] @ B[N,K]^T ; tiles full (M,N mult of 128, K mult of 32).
// gridDim.y (m-strips) must be a multiple of 8 for the XCD remap.
template <int EPI>
__global__ __launch_bounds__(256, 4) void gemm_bt(
    const bf16* __restrict__ A, const bf16* __restrict__ Bw,
    const float* __restrict__ bias, const float* __restrict__ resid,
    void* __restrict__ Cout, int K, int lda, int ldb, int ldc,
    long batchA, long batchB, long batchC, float alpha,
    int causalSkip, int kLimit) {
  // --- XCD-aware remap: blocks dispatch round-robin over 8 XCDs (lin%8).
  // Map so each XCD owns whole m-strips (A reuse in its private L2),
  // with n varying fastest inside the XCD.
  const int nx = gridDim.x;
  const int lin = blockIdx.y * nx + blockIdx.x;
  const int xcd = lin & 7;
  const int t = lin >> 3;
  const int n_idx = t % nx;
  const int j_idx = t / nx;
  const int m0 = (xcd + 8 * j_idx) * BM;
  const int n0 = n_idx * BN;
  if (causalSkip && n0 > m0) return;  // fully-masked score tile
  const int bz = blockIdx.z;
  const bf16* Ab = A + (long)bz * batchA;
  const bf16* Bb = Bw + (long)bz * batchB;
  const int kEnd = kLimit ? ((m0 + BM < K) ? (m0 + BM) : K) : K;

  __shared__ bf16 As[BM * BK];
  __shared__ bf16 Bs[BN * BK];

  const int tid = threadIdx.x;
  const int wave = tid >> 6;
  const int lane = tid & 63;
  const int wr = wave >> 1;   // wave row in 2x2
  const int wc = wave & 1;    // wave col
  const int l16 = lane & 15;
  const int kq = lane >> 4;   // k-quad 0..3 (8 bf16 each)

  // --- staging pointers (hoisted; advance by BK per iter).
  // LDS granule g holds row r=g>>2 and LOGICAL k-quad qc=(g&3)^((r>>1)&3):
  // the bank-conflict swizzle is applied on the GLOBAL source address since
  // global_load_lds's LDS destination is fixed lane-linear.
  const bf16* gAp[2];
  const bf16* gBp[2];
  bf16* lAp[2];
  bf16* lBp[2];
#pragma unroll
  for (int rep = 0; rep < 2; rep++) {
    const int c = tid + rep * 256;
    const int r = c >> 2;
    const int qc = (c & 3) ^ ((r >> 1) & 3);
    gAp[rep] = Ab + (long)(m0 + r) * lda + qc * 8;
    gBp[rep] = Bb + (long)(n0 + r) * ldb + qc * 8;
    lAp[rep] = As + (c & ~63) * 8;  // wave-uniform base; HW adds lane*16B
    lBp[rep] = Bs + (c & ~63) * 8;
  }

  // --- fragment LDS offsets (k-invariant, swizzled). swz=(l16>>1)&3 because
  // fragment row base is a multiple of 16.
  const int swz = (l16 >> 1) & 3;
  const int kqs = (kq ^ swz) * 8;
  int offA[4], offB[4];
#pragma unroll
  for (int i = 0; i < 4; i++) {
    offA[i] = (wr * 64 + i * 16 + l16) * BK + kqs;
    offB[i] = (wc * 64 + i * 16 + l16) * BK + kqs;
  }

  f32x4 acc[4][4] = {};

  for (int k0 = 0; k0 < kEnd; k0 += BK) {
#pragma unroll
    for (int rep = 0; rep < 2; rep++) {
      async_load16(gAp[rep], lAp[rep]);
      async_load16(gBp[rep], lBp[rep]);
      gAp[rep] += BK;
      gBp[rep] += BK;
    }
    __syncthreads();  // drains vmcnt(0): LDS data visible
    bf16x8 af[4], bfr[4];
#pragma unroll
    for (int i = 0; i < 4; i++) af[i] = *(const bf16x8*)(As + offA[i]);
#pragma unroll
    for (int j = 0; j < 4; j++) bfr[j] = *(const bf16x8*)(Bs + offB[j]);
#pragma unroll
    for (int i = 0; i < 4; i++)
#pragma unroll
      for (int j = 0; j < 4; j++)
        acc[i][j] = __builtin_amdgcn_mfma_f32_16x16x32_bf16(af[i], bfr[j],
                                                            acc[i][j], 0, 0, 0);
    __syncthreads();  // all reads done before next stage overwrites LDS
  }

  // C/D layout: col = lane&15, row = (lane>>4)*4 + reg  [m89/m91 verified]
  const int baseRow = m0 + wr * 64 + (lane >> 4) * 4;
  const int baseCol = n0 + wc * 64 + l16;
#pragma unroll
  for (int j = 0; j < 4; j++) {
    const int col = baseCol + j * 16;
    float bv = 0.0f;
    if (EPI != EPI_F32SCALE && bias != nullptr) bv = bias[col];
#pragma unroll
    for (int i = 0; i < 4; i++) {
      const int row0 = baseRow + i * 16;
#pragma unroll
      for (int r = 0; r < 4; r++) {
        const float v = acc[i][j][r];
        const long idx = (long)bz * batchC + (long)(row0 + r) * ldc + col;
        if (EPI == EPI_F32SCALE) {
          ((float*)Cout)[idx] = v * alpha;
        } else if (EPI == EPI_RESID) {
          ((float*)Cout)[idx] = resid[idx] + v + bv;
        } else if (EPI == EPI_GELU) {
          const float u = v + bv;
          const float g = 0.5f * u * (1.0f + erff(u * 0.70710678118654752f));
          ((bf16*)Cout)[idx] = (bf16)g;
        } else {
          ((bf16*)Cout)[idx] = (bf16)(v + bv);
        }
      }
    }
  }
}

// LayerNorm: one block per row of 1024, fp32 in -> bf16 out
__global__ __launch_bounds__(256) void ln_kernel(
    const float* __restrict__ x, const float* __restrict__ w,
    const float* __restrict__ b, bf16* __restrict__ out) {
  const int C = 1024;
  const long row = blockIdx.x;
  const int t = threadIdx.x;
  const float4 v = ((const float4*)(x + row * C))[t];
  float s = v.x + v.y + v.z + v.w;
  float sq = v.x * v.x + v.y * v.y + v.z * v.z + v.w * v.w;
#pragma unroll
  for (int o = 1; o < 64; o <<= 1) {
    s += __shfl_xor(s, o, 64);
    sq += __shfl_xor(sq, o, 64);
  }
  __shared__ float rs[4], rq[4];
  const int wv = t >> 6, ln = t & 63;
  if (!ln) { rs[wv] = s; rq[wv] = sq; }
  __syncthreads();
  s = rs[0] + rs[1] + rs[2] + rs[3];
  sq = rq[0] + rq[1] + rq[2] + rq[3];
  const float mean = s * (1.0f / 1024.0f);
  const float var = sq * (1.0f / 1024.0f) - mean * mean;
  const float rstd = rsqrtf(var + 1e-5f);
  const float4 wv4 = ((const float4*)w)[t];
  const float4 bv4 = ((const float4*)b)[t];
  bf16x4 o = {(bf16)((v.x - mean) * rstd * wv4.x + bv4.x),
              (bf16)((v.y - mean) * rstd * wv4.y + bv4.y),
              (bf16)((v.z - mean) * rstd * wv4.z + bv4.z),
              (bf16)((v.w - mean) * rstd * wv4.w + bv4.w)};
  ((bf16x4*)(out + row * C))[t] = o;
}

// Causal softmax over fp32 scores row (already scaled) -> bf16 P, zeros for s>t
__global__ __launch_bounds__(256) void softmax_causal(
    const float* __restrict__ S, bf16* __restrict__ P) {
  const int T = 2048;
  const int t = blockIdx.x, b = blockIdx.y;
  const long rowoff = ((long)b * T + t) * (long)T;
  const float* row = S + rowoff;
  bf16* prow = P + rowoff;
  const int L = t + 1;
  const int tid = threadIdx.x;
  float vals[8];
  float mx = -1e30f;
#pragma unroll
  for (int i = 0; i < 8; i++) {
    const int idx = tid + i * 256;
    if (idx < L) {
      vals[i] = row[idx];
      mx = fmaxf(mx, vals[i]);
    } else {
      vals[i] = -1e30f;
    }
  }
#pragma unroll
  for (int o = 1; o < 64; o <<= 1) mx = fmaxf(mx, __shfl_xor(mx, o, 64));
  __shared__ float red[4], red2[4];
  const int wv = tid >> 6, ln = tid & 63;
  if (!ln) red[wv] = mx;
  __syncthreads();
  mx = fmaxf(fmaxf(red[0], red[1]), fmaxf(red[2], red[3]));
  float sum = 0.0f;
#pragma unroll
  for (int i = 0; i < 8; i++) {
    const int idx = tid + i * 256;
    const float e = (idx < L) ? __expf(vals[i] - mx) : 0.0f;
    vals[i] = e;
    sum += e;
  }
#pragma unroll
  for (int o = 1; o < 64; o <<= 1) sum += __shfl_xor(sum, o, 64);
  if (!ln) red2[wv] = sum;
  __syncthreads();
  sum = red2[0] + red2[1] + red2[2] + red2[3];
  const float inv = 1.0f / sum;
#pragma unroll
  for (int i = 0; i < 8; i++) prow[tid + i * 256] = (bf16)(vals[i] * inv);
}

// V transpose: qkv[b, s, 2048+c] -> vt[b, c, s]  (bf16)
__global__ __launch_bounds__(256) void transpose_v(
    const bf16* __restrict__ qkv, bf16* __restrict__ vt) {
  const int T = 2048, C3 = 3072, C = 1024, COFF = 2048;
  __shared__ bf16 tile[32][33];
  const int b = blockIdx.z;
  const int s0 = blockIdx.x * 32, c0 = blockIdx.y * 32;
  const int tx = threadIdx.x & 31, ty0 = threadIdx.x >> 5;
#pragma unroll
  for (int j = 0; j < 4; j++) {
    const int ty = ty0 + j * 8;
    tile[ty][tx] = qkv[((long)b * T + s0 + ty) * C3 + COFF + c0 + tx];
  }
  __syncthreads();
#pragma unroll
  for (int j = 0; j < 4; j++) {
    const int ty = ty0 + j * 8;
    vt[(long)b * C * T + (long)(c0 + ty) * T + s0 + tx] = tile[tx][ty];
  }
}

__global__ void f2bf_kernel(const float* __restrict__ in,
                            bf16* __restrict__ out, long n4) {
  const long i = (long)blockIdx.x * blockDim.x + threadIdx.x;
  if (i < n4) {
    const float4 v = ((const float4*)in)[i];
    bf16x4 o = {(bf16)v.x, (bf16)v.y, (bf16)v.z, (bf16)v.w};
    ((bf16x4*)out)[i] = o;
  }
}

extern "C" void kernel_launch(void* const* d_in, const int* in_sizes, int n_in,
                              void* d_out, int out_size, void* d_ws,
                              size_t ws_size, hipStream_t stream) {
  const int Bb = 4, T = 2048, C = 1024, FF = 4096, NB = 8;
  const int M = Bb * T;  // 8192
  const float* x_in = (const float*)d_in[0];
  const float* ln1_w = (const float*)d_in[1];
  const float* ln1_b = (const float*)d_in[2];
  const float* qkv_w = (const float*)d_in[3];
  const float* qkv_b = (const float*)d_in[4];
  const float* out_w = (const float*)d_in[5];
  const float* out_b = (const float*)d_in[6];
  const float* ln2_w = (const float*)d_in[7];
  const float* ln2_b = (const float*)d_in[8];
  const float* ff0_w = (const float*)d_in[9];
  const float* ff0_b = (const float*)d_in[10];
  const float* ff3_w = (const float*)d_in[11];
  const float* ff3_b = (const float*)d_in[12];
  float* x = (float*)d_out;  // fp32 residual stream lives in d_out

  char* p = (char*)d_ws;
  auto alloc = [&](size_t bytes) {
    char* r = p;
    p += (bytes + 255) & ~(size_t)255;
    return r;
  };
  bf16* wqkv = (bf16*)alloc((size_t)NB * 3 * C * C * 2);
  bf16* wout = (bf16*)alloc((size_t)NB * C * C * 2);
  bf16* wff0 = (bf16*)alloc((size_t)NB * FF * C * 2);
  bf16* wff3 = (bf16*)alloc((size_t)NB * C * FF * 2);
  bf16* hbuf = (bf16*)alloc((size_t)M * C * 2);
  bf16* qkvb = (bf16*)alloc((size_t)M * 3 * C * 2);
  float* att = (float*)alloc((size_t)Bb * T * T * 4);
  bf16* pbuf = (bf16*)alloc((size_t)Bb * T * T * 2);
  bf16* vt = (bf16*)alloc((size_t)Bb * C * T * 2);
  bf16* aout = (bf16*)alloc((size_t)M * C * 2);
  bf16* ffb = (bf16*)att;  // FF intermediate aliases scores buffer (phase-disjoint)

  auto conv = [&](const float* src, bf16* dst, long n) {
    const long n4 = n / 4;
    f2bf_kernel<<<dim3((unsigned)((n4 + 255) / 256)), dim3(256), 0, stream>>>(
        src, dst, n4);
  };
  conv(qkv_w, wqkv, (long)NB * 3 * C * C);
  conv(out_w, wout, (long)NB * C * C);
  conv(ff0_w, wff0, (long)NB * FF * C);
  conv(ff3_w, wff3, (long)NB * C * FF);

  hipMemcpyAsync(x, x_in, (size_t)M * C * 4, hipMemcpyDeviceToDevice, stream);

  const float scale = 1.0f / 32.0f;  // 1/sqrt(C)

  for (int blk = 0; blk < NB; blk++) {
    const bf16* wq = wqkv + (long)blk * 3 * C * C;
    const bf16* wo = wout + (long)blk * C * C;
    const bf16* w0 = wff0 + (long)blk * FF * C;
    const bf16* w3 = wff3 + (long)blk * C * FF;
    const float* l1w = ln1_w + blk * C;
    const float* l1b = ln1_b + blk * C;
    const float* l2w = ln2_w + blk * C;
    const float* l2b = ln2_b + blk * C;
    const float* qb = qkv_b + blk * 3 * C;
    const float* ob = out_b + blk * C;
    const float* f0b = ff0_b + blk * FF;
    const float* f3b = ff3_b + blk * C;

    // h = LN1(x)
    ln_kernel<<<dim3(M), dim3(256), 0, stream>>>(x, l1w, l1b, hbuf);
    // qkv = h @ Wqkv^T + b
    gemm_bt<EPI_BF16><<<dim3(3 * C / BN, M / BM), dim3(256), 0, stream>>>(
        hbuf, wq, qb, nullptr, qkvb, C, C, C, 3 * C, 0, 0, 0, 1.0f, 0, 0);
    // S = q @ k^T * scale (causal tile skip), per batch
    gemm_bt<EPI_F32SCALE><<<dim3(T / BN, T / BM, Bb), dim3(256), 0, stream>>>(
        qkvb, qkvb + C, nullptr, nullptr, att, C, 3 * C, 3 * C, T,
        (long)T * 3 * C, (long)T * 3 * C, (long)T * T, scale, 1, 0);
    // P = softmax(S) causal, bf16
    softmax_causal<<<dim3(T, Bb), dim3(256), 0, stream>>>(att, pbuf);
    // vt = v^T
    transpose_v<<<dim3(T / 32, C / 32, Bb), dim3(256), 0, stream>>>(qkvb, vt);
    // attn_out = P @ V   (K limited to m0+BM by causality)
    gemm_bt<EPI_BF16><<<dim3(C / BN, T / BM, Bb), dim3(256), 0, stream>>>(
        pbuf, vt, nullptr, nullptr, aout, T, T, T, C, (long)T * T, (long)C * T,
        (long)T * C, 1.0f, 0, 1);
    // x = x + attn_out @ Wo^T + bo
    gemm_bt<EPI_RESID><<<dim3(C / BN, M / BM), dim3(256), 0, stream>>>(
        aout, wo, ob, x, x, C, C, C, C, 0, 0, 0, 1.0f, 0, 0);
    // h = LN2(x)
    ln_kernel<<<dim3(M), dim3(256), 0, stream>>>(x, l2w, l2b, hbuf);
    // ff = gelu(h @ W0^T + b0)
    gemm_bt<EPI_GELU><<<dim3(FF / BN, M / BM), dim3(256), 0, stream>>>(
        hbuf, w0, f0b, nullptr, ffb, C, C, C, FF, 0, 0, 0, 1.0f, 0, 0);
    // x = x + ff @ W3^T + b3
    gemm_bt<EPI_RESID><<<dim3(C / BN, M / BM), dim3(256), 0, stream>>>(
        ffb, w3, f3b, x, x, FF, FF, FF, C, 0, 0, 0, 1.0f, 0, 0);
  }
}